// Round 1
// baseline (396.738 us; speedup 1.0000x reference)
//
#include <hip/hip_runtime.h>

typedef unsigned int uint32;
typedef unsigned short u16;
typedef float fx4 __attribute__((ext_vector_type(4)));
typedef uint32 u32x4 __attribute__((ext_vector_type(4)));

typedef const __attribute__((address_space(1))) void gvoid;
typedef __attribute__((address_space(3))) void lvoid;

#define MFMA_BF16_16x16x32(acc, a, b) \
  asm("v_mfma_f32_16x16x32_bf16 %0, %1, %2, %0" : "+v"(acc) : "v"(a), "v"(b))

__device__ __forceinline__ u16 f2bf_rne(float f) {
  uint32 u = __builtin_bit_cast(uint32, f);
  u += 0x7FFFu + ((u >> 16) & 1u);
  return (u16)(u >> 16);
}

// ---------------------------------------------------------------------------
// K1: dec[t,r,d] = scales[t] * 0.25 * sum_k cw[idx[t,r,k], d]   (bf16 out)
// grid = 4096 blocks (one per (t,r) row), 256 threads
// ---------------------------------------------------------------------------
__global__ __launch_bounds__(256) void decode_kernel(
    const float* __restrict__ cw, const int* __restrict__ indices,
    const float* __restrict__ scales, u16* __restrict__ dec) {
  const int row = blockIdx.x;      // t*512 + r
  const int t = row >> 9;
  const int* ip = indices + (size_t)row * 4;
  const float* c0 = cw + (size_t)ip[0] * 4096;
  const float* c1 = cw + (size_t)ip[1] * 4096;
  const float* c2 = cw + (size_t)ip[2] * 4096;
  const float* c3 = cw + (size_t)ip[3] * 4096;
  const float s = scales[t] * 0.25f;
  u16* orow = dec + (size_t)row * 4096;
  const int tid = threadIdx.x;
#pragma unroll
  for (int j = 0; j < 4; ++j) {
    const int d = j * 1024 + tid * 4;
    float4 a = *(const float4*)(c0 + d);
    float4 b = *(const float4*)(c1 + d);
    float4 c = *(const float4*)(c2 + d);
    float4 e = *(const float4*)(c3 + d);
    ushort4 o;
    o.x = f2bf_rne((a.x + b.x + c.x + e.x) * s);
    o.y = f2bf_rne((a.y + b.y + c.y + e.y) * s);
    o.z = f2bf_rne((a.z + b.z + c.z + e.z) * s);
    o.w = f2bf_rne((a.w + b.w + c.w + e.w) * s);
    *(ushort4*)(orow + d) = o;
  }
}

// ---------------------------------------------------------------------------
// K2: x (fp32) -> bf16. 2048 blocks x 256 threads x float4 = 2^21 elems
// ---------------------------------------------------------------------------
__global__ __launch_bounds__(256) void cvtx_kernel(const float* __restrict__ x,
                                                   u16* __restrict__ xb) {
  const int i = blockIdx.x * 256 + threadIdx.x;
  float4 v = ((const float4*)x)[i];
  ushort4 o;
  o.x = f2bf_rne(v.x);
  o.y = f2bf_rne(v.y);
  o.z = f2bf_rne(v.z);
  o.w = f2bf_rne(v.w);
  ((ushort4*)xb)[i] = o;
}

// ---------------------------------------------------------------------------
// K3: z[t] = x_bf16 @ rot[t]^T      M=512, N=4096, K=4096, B is fp32 in HBM
// 128x128 tile, BK=32, 4 waves, 16x16x32 bf16 MFMA, fp32 B staged to LDS via
// global_load_lds (source inverse-XOR-swizzled; reads XOR-swizzled -> ~2-way)
// and truncated to bf16 in-register with v_perm_b32.
// grid = 8 tiles * 4 * 32 = 1024 blocks, XCD-chunk swizzled.
// ---------------------------------------------------------------------------
__global__ __launch_bounds__(256, 2) void gemm_z_kernel(
    const u16* __restrict__ Xb,   // [512][4096] bf16
    const float* __restrict__ rot,// [8][4096][4096] fp32
    u16* __restrict__ Z) {        // [8][512][4096] bf16
  __shared__ char sA[8192];       // 128 x 32 bf16
  __shared__ char sB[16384];      // 128 x 32 fp32 (xor-swizzled slots)
  const int lb = blockIdx.x;
  const int swz = ((lb & 7) << 7) | (lb >> 3);  // XCD-chunked (1024 % 8 == 0)
  const int t = swz >> 7;
  const int rem = swz & 127;
  const int nb = rem >> 2, mb = rem & 3;        // sharers of a B-panel adjacent
  const float* Bt = rot + ((size_t)t << 24);
  u16* Ct = Z + ((size_t)t << 21);
  const int aRow0 = mb << 7, bCol0 = nb << 7;
  const int tid = threadIdx.x;
  const int wv = tid >> 6, ln = tid & 63;
  const int lr = ln & 15, lk = ln >> 4;
  const int wr = wv >> 1, wc = wv & 1;

  fx4 acc[4][4] = {};

  const int rowA_l = ln >> 2;          // + seg*16
  const int kkA = (ln & 3) * 8;        // bf16 elems
  const int rowB_l = ln >> 3;          // + seg*8

  for (int k0 = 0; k0 < 4096; k0 += 32) {
    // ---- stage A tile (8 KB): 8 x 1KB wave-segments, linear ----
#pragma unroll
    for (int c = 0; c < 2; ++c) {
      const int seg = wv * 2 + c;
      const int row = seg * 16 + rowA_l;
      __builtin_amdgcn_global_load_lds(
          (gvoid*)(Xb + (size_t)(aRow0 + row) * 4096 + (k0 + kkA)),
          (lvoid*)(sA + seg * 1024 + ln * 16), 16, 0, 0);
    }
    // ---- stage B tile (16 KB) with inverse-swizzled global source ----
#pragma unroll
    for (int c = 0; c < 4; ++c) {
      const int seg = wv * 4 + c;
      const int row = seg * 8 + rowB_l;
      const int kf = ((ln & 7) ^ (row & 7)) * 4;   // fp32 elems within 32-chunk
      __builtin_amdgcn_global_load_lds(
          (gvoid*)(Bt + (size_t)(bCol0 + row) * 4096 + (k0 + kf)),
          (lvoid*)(sB + seg * 1024 + ln * 16), 16, 0, 0);
    }
    __syncthreads();

    u32x4 af[4], bf[4];
#pragma unroll
    for (int m = 0; m < 4; ++m) {
      const int row = wr * 64 + m * 16 + lr;
      af[m] = *(const u32x4*)(sA + row * 64 + lk * 16);
    }
#pragma unroll
    for (int n = 0; n < 4; ++n) {
      const int row = wc * 64 + n * 16 + lr;
      const int base = row * 128 + lk * 32;
      const int sw = (row & 7) << 4;
      u32x4 u0 = *(const u32x4*)(sB + (base ^ sw));
      u32x4 u1 = *(const u32x4*)(sB + ((base + 16) ^ sw));
      u32x4 p;
      // pack truncated bf16 pairs: low16 = hi(f2k), high16 = hi(f2k+1)
      p[0] = __builtin_amdgcn_perm(u0[1], u0[0], 0x07060302u);
      p[1] = __builtin_amdgcn_perm(u0[3], u0[2], 0x07060302u);
      p[2] = __builtin_amdgcn_perm(u1[1], u1[0], 0x07060302u);
      p[3] = __builtin_amdgcn_perm(u1[3], u1[2], 0x07060302u);
      bf[n] = p;
    }
#pragma unroll
    for (int m = 0; m < 4; ++m)
#pragma unroll
      for (int n = 0; n < 4; ++n)
        MFMA_BF16_16x16x32(acc[m][n], af[m], bf[n]);
    __syncthreads();
  }

  // C/D layout: col = lane&15, row = (lane>>4)*4 + j
#pragma unroll
  for (int m = 0; m < 4; ++m) {
    const int r0 = aRow0 + wr * 64 + m * 16 + lk * 4;
#pragma unroll
    for (int n = 0; n < 4; ++n) {
      const int col = bCol0 + wc * 64 + n * 16 + lr;
#pragma unroll
      for (int j = 0; j < 4; ++j)
        Ct[(size_t)(r0 + j) * 4096 + col] = f2bf_rne(acc[m][n][j]);
    }
  }
}

// ---------------------------------------------------------------------------
// K4: out[n, t*512 + r] = sum_d z[t,n,d] * dec[t,r,d] + bias[col]
// per tile: M=512, N=512, K=4096, both operands bf16. 128 blocks.
// ---------------------------------------------------------------------------
__global__ __launch_bounds__(256, 2) void gemm_out_kernel(
    const u16* __restrict__ Z,    // [8][512][4096]
    const u16* __restrict__ Dec,  // [8][512][4096]
    const float* __restrict__ bias,
    float* __restrict__ out) {    // [512][4096]
  __shared__ char sA[8192];
  __shared__ char sB[8192];
  const int lb = blockIdx.x;
  const int swz = ((lb & 7) << 4) | (lb >> 3);  // 128 % 8 == 0
  const int t = swz >> 4;
  const int rem = swz & 15;
  const int nb = rem >> 2, mb = rem & 3;
  const u16* At = Z + ((size_t)t << 21);
  const u16* Bt = Dec + ((size_t)t << 21);
  const int aRow0 = mb << 7, bCol0 = nb << 7;
  const int tid = threadIdx.x;
  const int wv = tid >> 6, ln = tid & 63;
  const int lr = ln & 15, lk = ln >> 4;
  const int wr = wv >> 1, wc = wv & 1;

  fx4 acc[4][4] = {};

  const int rowS_l = ln >> 2;
  const int kkS = (ln & 3) * 8;

  for (int k0 = 0; k0 < 4096; k0 += 32) {
#pragma unroll
    for (int c = 0; c < 2; ++c) {
      const int seg = wv * 2 + c;
      const int row = seg * 16 + rowS_l;
      __builtin_amdgcn_global_load_lds(
          (gvoid*)(At + (size_t)(aRow0 + row) * 4096 + (k0 + kkS)),
          (lvoid*)(sA + seg * 1024 + ln * 16), 16, 0, 0);
      __builtin_amdgcn_global_load_lds(
          (gvoid*)(Bt + (size_t)(bCol0 + row) * 4096 + (k0 + kkS)),
          (lvoid*)(sB + seg * 1024 + ln * 16), 16, 0, 0);
    }
    __syncthreads();

    u32x4 af[4], bf[4];
#pragma unroll
    for (int m = 0; m < 4; ++m)
      af[m] = *(const u32x4*)(sA + (wr * 64 + m * 16 + lr) * 64 + lk * 16);
#pragma unroll
    for (int n = 0; n < 4; ++n)
      bf[n] = *(const u32x4*)(sB + (wc * 64 + n * 16 + lr) * 64 + lk * 16);
#pragma unroll
    for (int m = 0; m < 4; ++m)
#pragma unroll
      for (int n = 0; n < 4; ++n)
        MFMA_BF16_16x16x32(acc[m][n], af[m], bf[n]);
    __syncthreads();
  }

#pragma unroll
  for (int n = 0; n < 4; ++n) {
    const int colg = (t << 9) + bCol0 + wc * 64 + n * 16 + lr;
    const float bv = bias[colg];
#pragma unroll
    for (int m = 0; m < 4; ++m) {
      const int r0 = aRow0 + wr * 64 + m * 16 + lk * 4;
#pragma unroll
      for (int j = 0; j < 4; ++j)
        out[(size_t)(r0 + j) * 4096 + colg] = acc[m][n][j] + bv;
    }
  }
}

// ---------------------------------------------------------------------------
extern "C" void kernel_launch(void* const* d_in, const int* in_sizes, int n_in,
                              void* d_out, int out_size, void* d_ws, size_t ws_size,
                              hipStream_t stream) {
  const float* x       = (const float*)d_in[0];   // [512][4096]
  const float* cw      = (const float*)d_in[1];   // [16384][4096]
  const int*   indices = (const int*)d_in[2];     // [8][512][4]
  const float* rot     = (const float*)d_in[3];   // [8][4096][4096]
  const float* scales  = (const float*)d_in[4];   // [8]
  const float* bias    = (const float*)d_in[5];   // [4096]
  float* out = (float*)d_out;
  char* ws = (char*)d_ws;

  u16* xb  = (u16*)(ws);                          // 4 MiB
  u16* dec = (u16*)(ws + ((size_t)4 << 20));      // 32 MiB
  u16* z   = (u16*)(ws + ((size_t)36 << 20));     // 32 MiB

  cvtx_kernel<<<dim3(2048), dim3(256), 0, stream>>>(x, xb);
  decode_kernel<<<dim3(4096), dim3(256), 0, stream>>>(cw, indices, scales, dec);
  gemm_z_kernel<<<dim3(1024), dim3(256), 0, stream>>>(xb, rot, z);
  gemm_out_kernel<<<dim3(128), dim3(256), 0, stream>>>(z, dec, bias, out);
}